// Round 3
// baseline (91.370 us; speedup 1.0000x reference)
//
#include <hip/hip_runtime.h>
#include <math.h>

#define BATCH 16
#define NPRED 25000
#define MTGT  64
#define CHUNKS 64
#define PPC   400                 // preds per chunk (64*400 = 25600 >= 25000)
#define ABLK  512                 // 8 waves per block
#define WAVES (ABLK / 64)
#define PPW   (PPC / WAVES)       // 50 preds per wave

// ws layout (no zero-init needed anywhere — everything fully overwritten):
//   part[B][CHUNKS][MTGT]  u64   at 0        (16*64*64*8 = 512 KB)
//   focalp[B][CHUNKS]      float at PART_BYTES (4 KB)
#define PART_BYTES ((size_t)BATCH * CHUNKS * MTGT * 8)

__device__ __forceinline__ float focal_term(float x, float t) {
    // mirrors reference focal_loss elementwise (ALPHA=0.25, GAMMA=2)
    float prob = 1.0f / (1.0f + expf(-x));
    float ce = fmaxf(x, 0.0f) - x * t + log1pf(expf(-fabsf(x)));
    float p_t = prob * t + (1.0f - prob) * (1.0f - t);
    float alpha_t = 0.25f * t + 0.75f * (1.0f - t);
    p_t = fminf(fmaxf(p_t, 1e-6f), 1.0f - 1e-6f);
    float om = 1.0f - p_t;
    return alpha_t * om * om * ce;
}

__global__ __launch_bounds__(ABLK) void iou_argmax_kernel(
    const float* __restrict__ preds,    // (B, N, 5)
    const float* __restrict__ targets,  // (B, M, 4) xyxy
    unsigned long long* __restrict__ part,  // (B, CHUNKS, M) plain-stored
    float* __restrict__ focalp)             // (B, CHUNKS) plain-stored
{
    const int b = blockIdx.y;
    const int chunk = blockIdx.x;
    const int t = threadIdx.x;
    const int lane = t & 63;
    const int w = t >> 6;

    __shared__ float4 sbox[PPC];                       // xyxy
    __shared__ unsigned long long comb[WAVES][MTGT];
    __shared__ float sfocal[WAVES];

    // ---- stage preds -> LDS (xyxy), accumulate focal(conf, 0) partial ----
    float fsum = 0.0f;
    if (t < PPC) {
        int n = chunk * PPC + t;
        float4 bx;
        if (n < NPRED) {
            const float* p = preds + ((long)b * NPRED + n) * 5;
            float cx = p[0], cy = p[1];
            float wd = fmaxf(p[2], 1e-4f);
            float hh = fmaxf(p[3], 1e-4f);
            bx.x = cx - wd / 2.0f;
            bx.y = cy - hh / 2.0f;
            bx.z = cx + wd / 2.0f;
            bx.w = cy + hh / 2.0f;
            fsum = focal_term(p[4], 0.0f);
        } else {
            bx = make_float4(3e8f, 3e8f, 3e8f, 3e8f);  // sentinel: iou = 0
        }
        sbox[t] = bx;
    }
    // wave-reduce focal partial
    for (int off = 32; off > 0; off >>= 1) fsum += __shfl_down(fsum, off);
    if (lane == 0) sfocal[w] = fsum;

    // ---- my target (lane = target index) ----
    const float* tg = targets + ((long)b * MTGT + lane) * 4;
    float tx1 = tg[0], ty1 = tg[1], tx2 = tg[2], ty2 = tg[3];
    float ta = (tx2 - tx1) * (ty2 - ty1);

    __syncthreads();

    // ---- wave w scans preds [w*PPW, (w+1)*PPW); lane = its own target ----
    // unroll-by-2 pair tournament: halves the best-chain dependency length.
    const int nbase = chunk * PPC + w * PPW;
    float bi = 0.0f, bd = 1.0f;
    int bn = nbase;
#pragma unroll 5
    for (int j = 0; j < PPW; j += 2) {
        float4 b0 = sbox[w * PPW + j];                 // LDS broadcast reads
        float4 b1 = sbox[w * PPW + j + 1];

        float a0 = (b0.z - b0.x) * (b0.w - b0.y);
        float i0 = fmaxf(fminf(b0.z, tx2) - fmaxf(b0.x, tx1), 0.0f) *
                   fmaxf(fminf(b0.w, ty2) - fmaxf(b0.y, ty1), 0.0f);
        float d0 = a0 + ta - i0;

        float a1 = (b1.z - b1.x) * (b1.w - b1.y);
        float i1 = fmaxf(fminf(b1.z, tx2) - fmaxf(b1.x, tx1), 0.0f) *
                   fmaxf(fminf(b1.w, ty2) - fmaxf(b1.y, ty1), 0.0f);
        float d1 = a1 + ta - i1;

        // pair winner: j+1 only on strictly greater (first-index tie-break)
        bool w1 = (i1 * d0) > (i0 * d1);
        float wi = w1 ? i1 : i0;
        float wd = w1 ? d1 : d0;
        int wn = nbase + j + (w1 ? 1 : 0);

        // vs running best: best is earlier index, wins ties
        bool up = (wi * bd) > (bi * wd);
        bi = up ? wi : bi;
        bd = up ? wd : bd;
        bn = up ? wn : bn;
    }
    float iou = bi / bd;  // exact IEEE div on reference-identical operands
    comb[w][lane] =
        ((unsigned long long)__float_as_uint(iou) << 32) | (unsigned int)(~bn);

    __syncthreads();

    if (t < MTGT) {
        unsigned long long v = comb[0][t];
#pragma unroll
        for (int ww = 1; ww < WAVES; ww++) {
            unsigned long long o = comb[ww][t];
            v = (o > v) ? o : v;
        }
        part[((long)b * CHUNKS + chunk) * MTGT + t] = v;  // plain store, no init
    }
    if (t == 0) {
        float s = sfocal[0];
#pragma unroll
        for (int ww = 1; ww < WAVES; ww++) s += sfocal[ww];
        focalp[b * CHUNKS + chunk] = s;
    }
}

__global__ __launch_bounds__(1024) void finalize_kernel(
    const float* __restrict__ preds,
    const float* __restrict__ targets,
    const unsigned long long* __restrict__ part,
    const float* __restrict__ focalp,
    float* __restrict__ out)  // single block: plain store, no init
{
    const int t = threadIdx.x;
    const int b = t >> 6;       // wave = batch
    const int lane = t & 63;    // lane = target index (and chunk index for focal)

    __shared__ float sper[BATCH];

    // reduce per-target argmax over chunks (coalesced: lane-contiguous u64)
    unsigned long long best = 0ull;
    const unsigned long long* pp = part + (long)b * CHUNKS * MTGT + lane;
#pragma unroll 8
    for (int c = 0; c < CHUNKS; c++) {
        unsigned long long v = pp[c * MTGT];
        best = (v > best) ? v : best;
    }
    int id = (int)(~(unsigned int)best);

    const float* tgp = targets + ((long)b * MTGT + lane) * 4;
    float x1t = tgp[0], y1t = tgp[1], x2t = tgp[2], y2t = tgp[3];

    // recompute exact pairwise IoU of (winner pred, my target) for threshold
    float x1p = 0.f, y1p = 0.f, x2p = 0.f, y2p = 0.f, cf = 0.f;
    float v = 0.0f;
    if (id >= 0 && id < NPRED) {
        const float* p = preds + ((long)b * NPRED + id) * 5;
        float cx = p[0], cy = p[1];
        float wd = fmaxf(p[2], 1e-4f);
        float hh = fmaxf(p[3], 1e-4f);
        cf = p[4];
        x1p = cx - wd / 2.0f; y1p = cy - hh / 2.0f;
        x2p = cx + wd / 2.0f; y2p = cy + hh / 2.0f;
        float ltx = fmaxf(x1p, x1t), lty = fmaxf(y1p, y1t);
        float rbx = fminf(x2p, x2t), rby = fminf(y2p, y2t);
        float inter = fmaxf(rbx - ltx, 0.0f) * fmaxf(rby - lty, 0.0f);
        float ap = (x2p - x1p) * (y2p - y1p);
        float at = (x2t - x1t) * (y2t - y1t);
        v = inter / (ap + at - inter);
    }

    // greedy match in-register: lane m accepted iff iou>thr and pred unclaimed
    bool accepted = false;
    for (int m = 0; m < MTGT; m++) {
        float vm = __shfl(v, m);
        int im = __shfl(id, m);
        unsigned long long conflict = __ballot(accepted && (id == im));
        bool ok = (vm > 0.2f) && (conflict == 0ull);
        if (lane == m) accepted = ok;
    }

    float csum = 0.0f, dsum = 0.0f;
    int cnt = 0;
    if (accepted) {
        // ciou_loss, op-order per reference, EPS=1e-7
        float ltx = fmaxf(x1p, x1t), lty = fmaxf(y1p, y1t);
        float rbx = fminf(x2p, x2t), rby = fminf(y2p, y2t);
        float inter = fmaxf(rbx - ltx, 0.0f) * fmaxf(rby - lty, 0.0f);
        float uni = (x2p - x1p) * (y2p - y1p) + (x2t - x1t) * (y2t - y1t) - inter;
        float iou = inter / (uni + 1e-7f);
        float cx1 = fminf(x1p, x1t), cy1 = fminf(y1p, y1t);
        float cx2 = fmaxf(x2p, x2t), cy2 = fmaxf(y2p, y2t);
        float dx = cx2 - cx1, dy = cy2 - cy1;
        float diag = dx * dx + dy * dy + 1e-7f;
        float ex = x1p + x2p - x1t - x2t;
        float ey = y1p + y2p - y1t - y2t;
        float centers = (ex * ex + ey * ey) / 4.0f;
        float diou = 1.0f - iou + centers / diag;
        float wp = x2p - x1p, hp = y2p - y1p;
        float wt = x2t - x1t, ht = y2t - y1t;
        float dat = atanf(wt / ht) - atanf(wp / hp);
        float vv = 0.40528473f * (dat * dat);  // 4/pi^2
        float alpha = vv / (1.0f - iou + vv + 1e-7f);
        csum = diou + alpha * vv;
        cnt = 1;
        dsum = focal_term(cf, 1.0f) - focal_term(cf, 0.0f);
    }

    // focal(conf,0) total for this batch: lane = chunk (CHUNKS == 64)
    float fsum = focalp[b * CHUNKS + lane];

    for (int off = 32; off > 0; off >>= 1) {
        csum += __shfl_down(csum, off);
        dsum += __shfl_down(dsum, off);
        fsum += __shfl_down(fsum, off);
        cnt  += __shfl_down(cnt, off);
    }
    if (lane == 0) {
        float conf = (fsum + dsum) / (float)NPRED;
        float per = conf;
        if (cnt > 0) per += csum / (float)cnt;
        sper[b] = per;
    }
    __syncthreads();
    if (t == 0) {
        float s = 0.0f;
#pragma unroll
        for (int bb = 0; bb < BATCH; bb++) s += sper[bb];
        out[0] = s * (1.0f / (float)BATCH);
    }
}

extern "C" void kernel_launch(void* const* d_in, const int* in_sizes, int n_in,
                              void* d_out, int out_size, void* d_ws, size_t ws_size,
                              hipStream_t stream) {
    const float* preds = (const float*)d_in[0];     // (16, 25000, 5) f32
    const float* targets = (const float*)d_in[1];   // (16, 64, 4) f32
    float* out = (float*)d_out;

    unsigned long long* part = (unsigned long long*)d_ws;
    float* focalp = (float*)((char*)d_ws + PART_BYTES);

    dim3 gridA(CHUNKS, BATCH);
    iou_argmax_kernel<<<gridA, ABLK, 0, stream>>>(preds, targets, part, focalp);
    finalize_kernel<<<1, 1024, 0, stream>>>(preds, targets, part, focalp, out);
}